// Round 1
// baseline (811.807 us; speedup 1.0000x reference)
//
#include <hip/hip_runtime.h>
#include <hip/hip_bf16.h>
#include <cstdint>
#include <cstddef>

#define N_EX_TOTAL   100000
#define N_EX_PAD     100096   // lcm(128,64) padded: 128*782 = 64*1564
#define N_TILES      1564     // N_EX_PAD / 64
#define DFEAT        256
#define DIN          1024
#define NLAB         28

typedef __attribute__((ext_vector_type(8))) short bf16x8;
typedef __attribute__((ext_vector_type(4))) float f32x4;

// RTNE float -> bf16 bits (inputs finite)
__device__ __forceinline__ unsigned short f2bf(float f){
  unsigned u = __float_as_uint(f);
  u += 0x7fffu + ((u >> 16) & 1u);
  return (unsigned short)(u >> 16);
}

// XOR swizzle: spreads 16B slots across banks for stride-128B/512B row reads (G4/T2)
__device__ __forceinline__ int swz(int row, int b){
  return b ^ ((row & 7) << 4);
}

__device__ __forceinline__ f32x4 mfma16(bf16x8 a, bf16x8 b, f32x4 c){
  return __builtin_amdgcn_mfma_f32_16x16x32_bf16(a, b, c, 0, 0, 0);
}

// ---------- tiny kernels ----------

__global__ __launch_bounds__(256)
void k_cvt_gw(const float* __restrict__ gw, unsigned short* __restrict__ gwb){
  int i = blockIdx.x * 256 + threadIdx.x;   // 262144 total
  gwb[i] = f2bf(gw[i]);
}

__global__ __launch_bounds__(256)
void k_zero(float* __restrict__ p, int n){
  int i = blockIdx.x * 256 + threadIdx.x;
  if (i < n) p[i] = 0.f;
}

__global__ __launch_bounds__(256)
void k_excr(const float* __restrict__ exc, unsigned short* __restrict__ excrb){
  int row = blockIdx.x * 256 + threadIdx.x;  // < 100096
  union { unsigned short u[32]; uint4 q[4]; } pk;
  #pragma unroll
  for (int k = 0; k < 32; ++k) pk.u[k] = 0;
  if (row < N_EX_TOTAL){
    float v[NLAB]; float ss = 0.f;
    #pragma unroll
    for (int k = 0; k < NLAB; ++k){ v[k] = exc[(size_t)row*NLAB + k]; ss += v[k]*v[k]; }
    float sc = 1.f / fmaxf(sqrtf(ss), 1e-12f);
    #pragma unroll
    for (int k = 0; k < NLAB; ++k) pk.u[k] = f2bf(v[k]*sc);
  }
  uint4* dst = (uint4*)(excrb + (size_t)row*32);
  #pragma unroll
  for (int i = 0; i < 4; ++i) dst[i] = pk.q[i];
}

__global__ __launch_bounds__(256)
void k_logits(const float* __restrict__ echo, float* __restrict__ out){
  int b = blockIdx.x * 256 + threadIdx.x;  // < 1024
  float e[NLAB]; float ss = 0.f;
  #pragma unroll
  for (int k = 0; k < NLAB; ++k){ e[k] = echo[(size_t)b*NLAB + k]; ss += e[k]*e[k]; }
  #pragma unroll
  for (int c = 0; c < NLAB; ++c)
    out[(size_t)b*NLAB + c] = -sqrtf(fmaxf(ss - 2.f*e[c] + 1.f, 0.f));
}

// ---------- projection GEMM + row L2 norm ----------
// C[M][256] = normalize_rows( A[M][1024] @ g_w.T ), output bf16.
// Block: 128 rows x 256 cols, 512 thr (8 waves: 4 in M x 2 in N). BK=64, K=1024.
__global__ __launch_bounds__(512)
void k_proj(const float* __restrict__ A, const unsigned short* __restrict__ gwb,
            unsigned short* __restrict__ outb, int M_in){
  __shared__ __align__(16) char sA[16384];   // [128][64] bf16, swizzled
  __shared__ __align__(16) char sB[32768];   // [256][64] bf16, swizzled
  __shared__ float rowsq[2][128];

  const int tid = threadIdx.x;
  const int lane = tid & 63;
  const int w = tid >> 6;
  const int wM = w >> 1, wN = w & 1;
  const int l15 = lane & 15, g = lane >> 4;
  const int bm0 = blockIdx.x * 128;

  const f32x4 fz = {0.f, 0.f, 0.f, 0.f};
  f32x4 acc[2][8];
  #pragma unroll
  for (int m = 0; m < 2; ++m)
    #pragma unroll
    for (int n = 0; n < 8; ++n) acc[m][n] = fz;

  const int sr = tid >> 2, sq = tid & 3;     // A-stage: 4 thr/row
  const int br = tid >> 1, bh = tid & 1;     // B-stage: 2 thr/row
  const int gr = bm0 + sr;
  const bool valid = (gr < M_in);

  for (int kb = 0; kb < 16; ++kb){
    const int k0 = kb * 64;
    { // stage A (fp32 -> bf16, swizzled)
      float4 fv[4];
      if (valid){
        const float4* src = (const float4*)(A + (size_t)gr*DIN + k0 + sq*16);
        #pragma unroll
        for (int i = 0; i < 4; ++i) fv[i] = src[i];
      } else {
        #pragma unroll
        for (int i = 0; i < 4; ++i) fv[i] = make_float4(0.f,0.f,0.f,0.f);
      }
      #pragma unroll
      for (int j = 0; j < 2; ++j){
        bf16x8 p;
        float4 a0 = fv[2*j], a1 = fv[2*j+1];
        p[0]=(short)f2bf(a0.x); p[1]=(short)f2bf(a0.y); p[2]=(short)f2bf(a0.z); p[3]=(short)f2bf(a0.w);
        p[4]=(short)f2bf(a1.x); p[5]=(short)f2bf(a1.y); p[6]=(short)f2bf(a1.z); p[7]=(short)f2bf(a1.w);
        *(bf16x8*)(sA + sr*128 + swz(sr, sq*32 + j*16)) = p;
      }
    }
    { // stage B (already bf16)
      const unsigned short* src = gwb + (size_t)br*DIN + k0 + bh*32;
      #pragma unroll
      for (int i = 0; i < 4; ++i){
        bf16x8 v = *(const bf16x8*)(src + i*8);
        *(bf16x8*)(sB + br*128 + swz(br, bh*64 + i*16)) = v;
      }
    }
    __syncthreads();

    bf16x8 af[2][2];
    #pragma unroll
    for (int m = 0; m < 2; ++m){
      const int r = 32*wM + 16*m + l15;
      #pragma unroll
      for (int kk = 0; kk < 2; ++kk)
        af[m][kk] = *(const bf16x8*)(sA + r*128 + swz(r, kk*64 + g*16));
    }
    #pragma unroll
    for (int kk = 0; kk < 2; ++kk)
      #pragma unroll
      for (int n = 0; n < 8; ++n){
        const int rb = 128*wN + 16*n + l15;
        bf16x8 bfv = *(const bf16x8*)(sB + rb*128 + swz(rb, kk*64 + g*16));
        #pragma unroll
        for (int m = 0; m < 2; ++m)
          acc[m][n] = mfma16(af[m][kk], bfv, acc[m][n]);
      }
    __syncthreads();
  }

  // row sum-of-squares: reduce over n (in-lane) then over 16-lane col group
  #pragma unroll
  for (int m = 0; m < 2; ++m){
    #pragma unroll
    for (int j = 0; j < 4; ++j){
      float ss = 0.f;
      #pragma unroll
      for (int n = 0; n < 8; ++n){ float v = acc[m][n][j]; ss += v*v; }
      ss += __shfl_xor(ss, 1);
      ss += __shfl_xor(ss, 2);
      ss += __shfl_xor(ss, 4);
      ss += __shfl_xor(ss, 8);
      if (l15 == 0) rowsq[wN][32*wM + 16*m + 4*g + j] = ss;
    }
  }
  __syncthreads();
  #pragma unroll
  for (int m = 0; m < 2; ++m){
    #pragma unroll
    for (int j = 0; j < 4; ++j){
      const int r = 32*wM + 16*m + 4*g + j;
      const float tot = rowsq[0][r] + rowsq[1][r];
      const float sc = 1.f / fmaxf(sqrtf(tot), 1e-12f);
      #pragma unroll
      for (int n = 0; n < 8; ++n){
        const int col = 128*wN + 16*n + l15;
        outb[(size_t)(bm0 + r)*DFEAT + col] = f2bf(acc[m][n][j]*sc);
      }
    }
  }
}

// ---------- fused  echo += (fn . efn^T)^3 @ excr ----------
// Block: 256 b-rows x 64-exemplar tiles. 512 thr = 8 waves, wave w owns rows 32w..32w+31.
// Q (fn frags) hoisted in registers; 2 barriers per tile.
__global__ __launch_bounds__(512)
void k_heavy(const unsigned short* __restrict__ fnb,
             const unsigned short* __restrict__ efnb,
             const unsigned short* __restrict__ excrb,
             float* __restrict__ echo){
  __shared__ __align__(16) char sE[32768];   // efn tile [64][256] bf16, swizzled
  __shared__ __align__(16) char sX[4096];    // excr tile [64][32] bf16, linear
  __shared__ __align__(16) char sP[32768];   // a-tile [256][64] bf16, swizzled (wave-private rows)

  const int tid = threadIdx.x;
  const int lane = tid & 63;
  const int w = tid >> 6;
  const int l15 = lane & 15, g = lane >> 4;
  const int bm0 = blockIdx.x * 256;
  const int wr0 = 32 * w;

  // Q hoist: 2 M-frags x 8 k-steps (fn is L2-resident)
  bf16x8 q[2][8];
  #pragma unroll
  for (int m = 0; m < 2; ++m){
    const size_t rb = (size_t)(bm0 + wr0 + 16*m + l15) * DFEAT;
    #pragma unroll
    for (int ks = 0; ks < 8; ++ks)
      q[m][ks] = *(const bf16x8*)(fnb + rb + ks*32 + g*8);
  }

  const f32x4 fz = {0.f, 0.f, 0.f, 0.f};
  f32x4 eacc[2][2];
  #pragma unroll
  for (int m = 0; m < 2; ++m){ eacc[m][0] = fz; eacc[m][1] = fz; }

  const int er = tid >> 3, ec = tid & 7;     // staging: 8 thr/row

  const int t0 = blockIdx.y * 8;
  const int t1 = (t0 + 8 < N_TILES) ? (t0 + 8) : N_TILES;

  for (int t = t0; t < t1; ++t){
    const int e0 = t * 64;
    { // stage efn tile
      const unsigned short* src = efnb + (size_t)(e0 + er)*DFEAT + ec*32;
      #pragma unroll
      for (int i = 0; i < 4; ++i){
        bf16x8 v = *(const bf16x8*)(src + i*8);
        *(bf16x8*)(sE + er*512 + swz(er, ec*64 + i*16)) = v;
      }
    }
    // stage excr tile (8B per thread)
    *(unsigned long long*)(sX + er*64 + ec*8) =
        *(const unsigned long long*)(excrb + (size_t)(e0 + er)*32 + ec*4);
    __syncthreads();

    // S = Q @ K^T for this tile
    f32x4 sa[2][4];
    #pragma unroll
    for (int m = 0; m < 2; ++m)
      #pragma unroll
      for (int n = 0; n < 4; ++n) sa[m][n] = fz;

    #pragma unroll
    for (int ks = 0; ks < 8; ++ks){
      #pragma unroll
      for (int n = 0; n < 4; ++n){
        const int rb = 16*n + l15;
        bf16x8 bfv = *(const bf16x8*)(sE + rb*512 + swz(rb, ks*64 + g*16));
        sa[0][n] = mfma16(q[0][ks], bfv, sa[0][n]);
        sa[1][n] = mfma16(q[1][ks], bfv, sa[1][n]);
      }
    }

    // a = s^3 -> bf16 -> sP (each wave writes only its own rows)
    #pragma unroll
    for (int m = 0; m < 2; ++m)
      #pragma unroll
      for (int n = 0; n < 4; ++n)
        #pragma unroll
        for (int j = 0; j < 4; ++j){
          const float s = sa[m][n][j];
          const int row = wr0 + 16*m + 4*g + j;
          const int col = 16*n + l15;
          *(short*)(sP + row*128 + swz(row, col*2)) = (short)f2bf(s*s*s);
        }

    // PV: echo-frags += a_tile @ excr_tile (reads own sP rows; compiler orders lgkmcnt)
    #pragma unroll
    for (int kk = 0; kk < 2; ++kk){
      bf16x8 pa[2];
      #pragma unroll
      for (int m = 0; m < 2; ++m){
        const int row = wr0 + 16*m + l15;
        pa[m] = *(const bf16x8*)(sP + row*128 + swz(row, kk*64 + g*16));
      }
      #pragma unroll
      for (int n = 0; n < 2; ++n){
        bf16x8 xb;
        #pragma unroll
        for (int j = 0; j < 8; ++j){
          const int e = kk*32 + g*8 + j;
          xb[j] = *(const short*)(sX + e*64 + (16*n + l15)*2);
        }
        #pragma unroll
        for (int m = 0; m < 2; ++m)
          eacc[m][n] = mfma16(pa[m], xb, eacc[m][n]);
      }
    }
    __syncthreads();
  }

  // accumulate into global echo
  #pragma unroll
  for (int m = 0; m < 2; ++m)
    #pragma unroll
    for (int n = 0; n < 2; ++n){
      const int col = 16*n + l15;
      if (col < NLAB){
        #pragma unroll
        for (int j = 0; j < 4; ++j){
          const int row = bm0 + wr0 + 16*m + 4*g + j;
          atomicAdd(echo + (size_t)row*NLAB + col, eacc[m][n][j]);
        }
      }
    }
}

// ---------- launch ----------

extern "C" void kernel_launch(void* const* d_in, const int* in_sizes, int n_in,
                              void* d_out, int out_size, void* d_ws, size_t ws_size,
                              hipStream_t stream){
  (void)in_sizes; (void)n_in; (void)out_size; (void)ws_size;
  const float* features    = (const float*)d_in[0];
  const float* ex_features = (const float*)d_in[1];
  const float* ex_classes  = (const float*)d_in[2];
  const float* g_w         = (const float*)d_in[3];
  // d_in[4] = class_reps = identity, folded into the math
  float* out = (float*)d_out;
  char* ws = (char*)d_ws;

  // ws layout (bytes):
  // [0, 512K)              gwb   : g_w as bf16 [256][1024]
  // [512K, 1M)             fnb   : normalized f as bf16 [1024][256]
  // [1M, 1M+51,249,152)    efnb  : normalized ef as bf16 [100096][256] (pad rows zero)
  // [52,297,728, +6,406,144) excrb: normalized ex_classes bf16 [100096][32] (cols 28..31 and pad rows zero)
  // [58,703,872, +114,688) echo  : fp32 [1024][28] accumulator
  unsigned short* gwb   = (unsigned short*)(ws + 0);
  unsigned short* fnb   = (unsigned short*)(ws + 524288u);
  unsigned short* efnb  = (unsigned short*)(ws + 1048576u);
  unsigned short* excrb = (unsigned short*)(ws + 52297728u);
  float* echo           = (float*)(ws + 58703872u);

  hipLaunchKernelGGL(k_cvt_gw, dim3(1024), dim3(256), 0, stream, g_w, gwb);
  hipLaunchKernelGGL(k_zero,   dim3(112),  dim3(256), 0, stream, echo, 1024*NLAB);
  hipLaunchKernelGGL(k_excr,   dim3(391),  dim3(256), 0, stream, ex_classes, excrb);
  hipLaunchKernelGGL(k_proj,   dim3(8),    dim3(512), 0, stream, features, gwb, fnb, 1024);
  hipLaunchKernelGGL(k_proj,   dim3(782),  dim3(512), 0, stream, ex_features, gwb, efnb, N_EX_TOTAL);
  hipLaunchKernelGGL(k_heavy,  dim3(4,196), dim3(512), 0, stream, fnb, efnb, excrb, echo);
  hipLaunchKernelGGL(k_logits, dim3(4),    dim3(256), 0, stream, echo, out);
}